// Round 1
// baseline (355.412 us; speedup 1.0000x reference)
//
#include <hip/hip_runtime.h>
#include <hip/hip_bf16.h>
#include <stdint.h>

// ---------------- problem constants ----------------
#define BB 2
#define TT 2048
#define DD 2048
#define HH 16
#define KVH 8
#define HDIM 128
#define BT (BB*TT)            // 4096
#define NQKV (HH*HDIM + 2*KVH*HDIM) // 4096
#define ATT_SCALE 0.08838834764831845f
#define RMS_EPS 1e-6f

typedef __bf16 bf16;
typedef __bf16 bf16x8 __attribute__((ext_vector_type(8)));
typedef __bf16 bf16x4 __attribute__((ext_vector_type(4)));
typedef float  f32x4  __attribute__((ext_vector_type(4)));

// async global->LDS, 16B per lane. LDS dest = wave-uniform base + lane*16.
__device__ __forceinline__ void gl_lds16(const void* g, const void* l) {
  __builtin_amdgcn_global_load_lds(
      (const __attribute__((address_space(1))) void*)(uintptr_t)g,
      (__attribute__((address_space(3))) void*)(uint32_t)(uintptr_t)l,
      16, 0, 0);
}

// ---------------- elementwise f32 -> bf16 cast ----------------
__global__ __launch_bounds__(256) void cast_bf16_k(const float* __restrict__ in,
                                                   bf16* __restrict__ out, int n4) {
  int i = blockIdx.x * blockDim.x + threadIdx.x;
  int stride = gridDim.x * blockDim.x;
  for (; i < n4; i += stride) {
    float4 v = ((const float4*)in)[i];
    bf16x4 o = { (bf16)v.x, (bf16)v.y, (bf16)v.z, (bf16)v.w };
    *(bf16x4*)(out + (size_t)i * 4) = o;
  }
}

// ---------------- f32 (R x C) -> bf16 (C x R) transpose-cast ----------------
__global__ __launch_bounds__(256) void transpose_cast_k(const float* __restrict__ in,
                                                        bf16* __restrict__ out,
                                                        int R, int C) {
  __shared__ float tile[32][33];
  int tx = threadIdx.x & 31, ty = threadIdx.x >> 5;
  int c0 = blockIdx.x * 32, r0 = blockIdx.y * 32;
#pragma unroll
  for (int i = 0; i < 4; ++i)
    tile[ty + 8*i][tx] = in[(size_t)(r0 + ty + 8*i) * C + c0 + tx];
  __syncthreads();
#pragma unroll
  for (int i = 0; i < 4; ++i)
    out[(size_t)(c0 + ty + 8*i) * R + r0 + tx] = (bf16)tile[tx][ty + 8*i];
}

// ---------------- bf16 V transpose: (B,T,KV,HD) -> (B,KV,HD,T) ----------------
__global__ __launch_bounds__(256) void transpose_v_k(const bf16* __restrict__ vb,
                                                     bf16* __restrict__ vbt) {
  __shared__ bf16 tile[32][33];
  int tx = threadIdx.x & 31, ty = threadIdx.x >> 5;
  int t0 = blockIdx.x * 32;
  int d0 = blockIdx.y * 32;
  int bk = blockIdx.z;                 // b*KV + kv
  int b = bk >> 3, kv = bk & 7;
#pragma unroll
  for (int i = 0; i < 4; ++i)
    tile[ty + 8*i][tx] = vb[(((size_t)(b*TT + t0 + ty + 8*i)) * KVH + kv) * HDIM + d0 + tx];
  __syncthreads();
#pragma unroll
  for (int i = 0; i < 4; ++i)
    vbt[(((size_t)bk) * HDIM + d0 + ty + 8*i) * TT + t0 + tx] = tile[tx][ty + 8*i];
}

// ---------------- GEMM C = A(MxK) * Bt(NxK)^T, m97 structure ----------------
// 128x128 tile, BK=32, 4 waves each 64x64 (4x4 frags of 16x16x32 bf16 MFMA)
template <int OUT_F32>
__global__ __launch_bounds__(256, 2)
void gemm_bt_k(const bf16* __restrict__ A, const bf16* __restrict__ Bt,
               void* __restrict__ Cout, int M, int N, int K) {
  __shared__ bf16 As[128 * 32];
  __shared__ bf16 Bs[128 * 32];
  const int tid = threadIdx.x;
  const int lane = tid & 63, wid = tid >> 6;
  const int lr = lane & 15, lq = lane >> 4;
  const int bm = blockIdx.y * 128, bn = blockIdx.x * 128;
  const int wr = wid >> 1, wc = wid & 1;
  const bf16* Ab = A + (size_t)bm * K;
  const bf16* Bb = Bt + (size_t)bn * K;
  f32x4 acc[4][4] = {};
  for (int k0 = 0; k0 < K; k0 += 32) {
#pragma unroll
    for (int r = 0; r < 2; ++r) {
      int ch = r * 256 + tid;
      int row = ch >> 2, c8 = ch & 3;
      const bf16* lbase = As + (size_t)(r * 256 + wid * 64) * 8;
      gl_lds16(Ab + (size_t)row * K + k0 + c8 * 8, lbase);
      const bf16* lbase2 = Bs + (size_t)(r * 256 + wid * 64) * 8;
      gl_lds16(Bb + (size_t)row * K + k0 + c8 * 8, lbase2);
    }
    __syncthreads();
    bf16x8 af[4], bfv[4];
#pragma unroll
    for (int m = 0; m < 4; ++m)
      af[m] = *(const bf16x8*)&As[(wr * 64 + m * 16 + lr) * 32 + lq * 8];
#pragma unroll
    for (int n = 0; n < 4; ++n)
      bfv[n] = *(const bf16x8*)&Bs[(wc * 64 + n * 16 + lr) * 32 + lq * 8];
#pragma unroll
    for (int m = 0; m < 4; ++m)
#pragma unroll
      for (int n = 0; n < 4; ++n)
        acc[m][n] = __builtin_amdgcn_mfma_f32_16x16x32_bf16(af[m], bfv[n], acc[m][n], 0, 0, 0);
    __syncthreads();
  }
#pragma unroll
  for (int m = 0; m < 4; ++m)
#pragma unroll
    for (int n = 0; n < 4; ++n)
#pragma unroll
      for (int r = 0; r < 4; ++r) {
        int row = bm + wr * 64 + m * 16 + lq * 4 + r;
        int col = bn + wc * 64 + n * 16 + lr;
        if (OUT_F32) ((float*)Cout)[(size_t)row * N + col] = acc[m][n][r];
        else         ((bf16*)Cout)[(size_t)row * N + col] = (bf16)acc[m][n][r];
      }
}

// ---------------- fused RMSNorm + RoPE + split ----------------
// qkv row (bf16, 4096): [q: h*128 | k: 2048+kv*128 | v: 3072+kv*128]
__global__ __launch_bounds__(256) void norm_rope_k(const bf16* __restrict__ qkv,
                                                   const float* __restrict__ qn_w,
                                                   const float* __restrict__ kn_w,
                                                   const float* __restrict__ sinb,
                                                   const float* __restrict__ cosb,
                                                   bf16* __restrict__ qro,
                                                   bf16* __restrict__ kro,
                                                   bf16* __restrict__ vo) {
  const int bt = blockIdx.x;
  const int tid = threadIdx.x, lane = tid & 63, wid = tid >> 6;
  const bf16* row = qkv + (size_t)bt * NQKV;
  const float sv = sinb[bt * 64 + lane];
  const float cv = cosb[bt * 64 + lane];
  for (int it = 0; it < 8; ++it) {
    int hv = it * 4 + wid;   // 0..31 : 0-15 q, 16-23 k, 24-31 v
    int off = (hv < 16) ? hv * 128 : (hv < 24) ? 2048 + (hv - 16) * 128 : 3072 + (hv - 24) * 128;
    float e0 = (float)row[off + lane];
    float e1 = (float)row[off + 64 + lane];
    if (hv >= 24) {
      bf16* dst = vo + (size_t)bt * (KVH * HDIM) + (hv - 24) * 128;
      dst[lane] = (bf16)e0;
      dst[64 + lane] = (bf16)e1;
    } else {
      float ss = e0 * e0 + e1 * e1;
#pragma unroll
      for (int o = 32; o >= 1; o >>= 1) ss += __shfl_xor(ss, o, 64);
      float rms = rsqrtf(ss * (1.0f / 128.0f) + RMS_EPS);
      const float* wn = (hv < 16) ? qn_w : kn_w;
      float n0 = e0 * rms * wn[lane];
      float n1 = e1 * rms * wn[lane + 64];
      float o0 = n0 * cv - n1 * sv;
      float o1 = n1 * cv + n0 * sv;
      if (hv < 16) {
        bf16* dst = qro + (size_t)bt * (HH * HDIM) + hv * 128;
        dst[lane] = (bf16)o0; dst[64 + lane] = (bf16)o1;
      } else {
        bf16* dst = kro + (size_t)bt * (KVH * HDIM) + (hv - 16) * 128;
        dst[lane] = (bf16)o0; dst[64 + lane] = (bf16)o1;
      }
    }
  }
}

// ---------------- GQA causal flash attention ----------------
// grid (T/64, H, B); 4 waves, each owns 16 q-rows. KVBLK=64.
// K LDS: [64][128] XOR-swizzled (chunk ^ (row&7)) via pre-swizzled global src.
// V LDS: [128][64] (from vbt, d-major) same swizzle. P: per-wave [16][64] swizzled.
__global__ __launch_bounds__(256, 2)
void attn_k(const bf16* __restrict__ qr, const bf16* __restrict__ kr,
            const bf16* __restrict__ vbt, bf16* __restrict__ ao) {
  __shared__ bf16 Ks[64 * 128];
  __shared__ bf16 Vst[128 * 64];
  __shared__ bf16 Ps[4 * 16 * 64];
  const int tid = threadIdx.x, lane = tid & 63, wid = tid >> 6;
  const int lr = lane & 15, lq = lane >> 4;
  const int qt = blockIdx.x, h = blockIdx.y, b = blockIdx.z;
  const int kvh = h >> 1;            // N_REP = 2
  const int q0 = qt * 64 + wid * 16;

  bf16x8 aq[4];
#pragma unroll
  for (int kk = 0; kk < 4; ++kk)
    aq[kk] = *(const bf16x8*)&qr[(((size_t)(b * TT + q0 + lr)) * HH + h) * HDIM + kk * 32 + lq * 8];

  f32x4 accO[8] = {};
  float mrun[4], lrun[4];
#pragma unroll
  for (int r = 0; r < 4; ++r) { mrun[r] = -INFINITY; lrun[r] = 0.f; }

  for (int kt = 0; kt <= qt; ++kt) {
    // ---- stage K tile (64x128) with pre-swizzled source ----
#pragma unroll
    for (int rd = 0; rd < 4; ++rd) {
      int ch = rd * 256 + tid;
      int row = ch >> 4, cc = ch & 15;
      int gcol = (cc ^ (row & 7)) * 8;
      gl_lds16(&kr[(((size_t)(b * TT + kt * 64 + row)) * KVH + kvh) * HDIM + gcol],
               Ks + (size_t)(rd * 256 + wid * 64) * 8);
    }
    // ---- stage V tile (128 d-rows x 64 t-cols) from vbt ----
#pragma unroll
    for (int rd = 0; rd < 4; ++rd) {
      int ch = rd * 256 + tid;
      int drow = ch >> 3, cc = ch & 7;
      int gcol = (cc ^ (drow & 7)) * 8;
      gl_lds16(&vbt[(((size_t)(b * KVH + kvh)) * HDIM + drow) * TT + kt * 64 + gcol],
               Vst + (size_t)(rd * 256 + wid * 64) * 8);
    }
    __syncthreads();

    // ---- S = Q K^T for 4 column tiles of 16 ----
    f32x4 sacc[4];
#pragma unroll
    for (int ct = 0; ct < 4; ++ct) {
      sacc[ct] = (f32x4){0.f, 0.f, 0.f, 0.f};
      int krow = ct * 16 + lr;
#pragma unroll
      for (int kk = 0; kk < 4; ++kk) {
        bf16x8 bk = *(const bf16x8*)((const char*)Ks + krow * 256 + (((kk * 4 + lq) ^ (krow & 7)) * 16));
        sacc[ct] = __builtin_amdgcn_mfma_f32_16x16x32_bf16(aq[kk], bk, sacc[ct], 0, 0, 0);
      }
    }

    // ---- mask, scale, online softmax (rows = lq*4+r, cols = ct*16+lr) ----
    float p[4][4];
    float pm[4] = {-INFINITY, -INFINITY, -INFINITY, -INFINITY};
#pragma unroll
    for (int ct = 0; ct < 4; ++ct) {
      int col = kt * 64 + ct * 16 + lr;
#pragma unroll
      for (int r = 0; r < 4; ++r) {
        int rowg = q0 + lq * 4 + r;
        float s = (col <= rowg) ? sacc[ct][r] * ATT_SCALE : -INFINITY;
        p[ct][r] = s;
        pm[r] = fmaxf(pm[r], s);
      }
    }
#pragma unroll
    for (int r = 0; r < 4; ++r) {
#pragma unroll
      for (int o = 1; o < 16; o <<= 1) pm[r] = fmaxf(pm[r], __shfl_xor(pm[r], o, 64));
    }
    float alpha[4], mnew[4];
#pragma unroll
    for (int r = 0; r < 4; ++r) {
      mnew[r] = fmaxf(mrun[r], pm[r]);
      alpha[r] = __expf(mrun[r] - mnew[r]);
      mrun[r] = mnew[r];
    }
    float rs[4] = {0.f, 0.f, 0.f, 0.f};
#pragma unroll
    for (int ct = 0; ct < 4; ++ct)
#pragma unroll
      for (int r = 0; r < 4; ++r) {
        float e = __expf(p[ct][r] - mnew[r]);
        p[ct][r] = e;
        rs[r] += e;
      }
#pragma unroll
    for (int r = 0; r < 4; ++r) {
#pragma unroll
      for (int o = 1; o < 16; o <<= 1) rs[r] += __shfl_xor(rs[r], o, 64);
      lrun[r] = lrun[r] * alpha[r] + rs[r];
    }

    // ---- write P to per-wave swizzled LDS ----
#pragma unroll
    for (int ct = 0; ct < 4; ++ct)
#pragma unroll
      for (int r = 0; r < 4; ++r) {
        int prow = lq * 4 + r;
        int col = ct * 16 + lr;
        int cc = col >> 3;
        char* pb = (char*)Ps + (wid * 16 + prow) * 128 + ((cc ^ (prow & 7)) * 16) + (col & 7) * 2;
        *(bf16*)pb = (bf16)p[ct][r];
      }

    // ---- rescale O ----
#pragma unroll
    for (int n = 0; n < 8; ++n)
#pragma unroll
      for (int r = 0; r < 4; ++r) accO[n][r] *= alpha[r];

    // ---- O += P V ----
#pragma unroll
    for (int c = 0; c < 2; ++c) {
      bf16x8 ap = *(const bf16x8*)((const char*)Ps + (wid * 16 + lr) * 128 + (((c * 4 + lq) ^ (lr & 7)) * 16));
#pragma unroll
      for (int n = 0; n < 8; ++n) {
        int drow = n * 16 + lr;
        bf16x8 bv = *(const bf16x8*)((const char*)Vst + drow * 128 + (((c * 4 + lq) ^ (drow & 7)) * 16));
        accO[n] = __builtin_amdgcn_mfma_f32_16x16x32_bf16(ap, bv, accO[n], 0, 0, 0);
      }
    }
    __syncthreads();
  }

  float inv[4];
#pragma unroll
  for (int r = 0; r < 4; ++r) inv[r] = 1.0f / lrun[r];
#pragma unroll
  for (int n = 0; n < 8; ++n)
#pragma unroll
    for (int r = 0; r < 4; ++r) {
      size_t idx = (((size_t)(b * TT + q0 + lq * 4 + r)) * HH + h) * HDIM + n * 16 + lr;
      ao[idx] = (bf16)(accO[n][r] * inv[r]);
    }
}

// ---------------- launcher ----------------
extern "C" void kernel_launch(void* const* d_in, const int* in_sizes, int n_in,
                              void* d_out, int out_size, void* d_ws, size_t ws_size,
                              hipStream_t stream) {
  const float* x    = (const float*)d_in[0];
  const float* wq   = (const float*)d_in[1];
  const float* wk   = (const float*)d_in[2];
  const float* wv   = (const float*)d_in[3];
  const float* wo   = (const float*)d_in[4];
  const float* qn_w = (const float*)d_in[5];
  const float* kn_w = (const float*)d_in[6];
  const float* sinb = (const float*)d_in[7];
  const float* cosb = (const float*)d_in[8];
  float* out = (float*)d_out;

  char* ws = (char*)d_ws;
  size_t off = 0;
  auto alloc = [&](size_t bytes) {
    char* p = ws + off;
    off += (bytes + 255) & ~(size_t)255;
    return p;
  };
  bf16* xb  = (bf16*)alloc((size_t)BT * DD * 2);       // x bf16 (reused as attn out)
  bf16* Wt  = (bf16*)alloc((size_t)NQKV * DD * 2);     // [wq|wk|wv]^T (reused as q_rope)
  bf16* Wot = (bf16*)alloc((size_t)DD * DD * 2);       // wo^T
  bf16* qkv = (bf16*)alloc((size_t)BT * NQKV * 2);     // fused qkv
  bf16* kro = (bf16*)alloc((size_t)BT * KVH * HDIM * 2);
  bf16* vb  = (bf16*)alloc((size_t)BT * KVH * HDIM * 2);
  bf16* vbt = (bf16*)alloc((size_t)BT * KVH * HDIM * 2);
  bf16* qro = Wt;   // alias: Wt dead after QKV GEMM
  bf16* aob = xb;   // alias: xb dead after QKV GEMM
  (void)ws_size; (void)in_sizes; (void)n_in; (void)out_size;

  cast_bf16_k<<<2048, 256, 0, stream>>>(x, xb, BT * DD / 4);
  transpose_cast_k<<<dim3(2048 / 32, 2048 / 32), 256, 0, stream>>>(wq, Wt, 2048, 2048);
  transpose_cast_k<<<dim3(1024 / 32, 2048 / 32), 256, 0, stream>>>(wk, Wt + (size_t)2048 * 2048, 2048, 1024);
  transpose_cast_k<<<dim3(1024 / 32, 2048 / 32), 256, 0, stream>>>(wv, Wt + (size_t)3072 * 2048, 2048, 1024);
  transpose_cast_k<<<dim3(2048 / 32, 2048 / 32), 256, 0, stream>>>(wo, Wot, 2048, 2048);

  gemm_bt_k<0><<<dim3(NQKV / 128, BT / 128), 256, 0, stream>>>(xb, Wt, qkv, BT, NQKV, DD);

  norm_rope_k<<<BT, 256, 0, stream>>>(qkv, qn_w, kn_w, sinb, cosb, qro, kro, vb);
  transpose_v_k<<<dim3(TT / 32, HDIM / 32, BB * KVH), 256, 0, stream>>>(vb, vbt);

  attn_k<<<dim3(TT / 64, HH, BB), 256, 0, stream>>>(qro, kro, vbt, aob);

  gemm_bt_k<1><<<dim3(DD / 128, BT / 128), 256, 0, stream>>>(aob, Wot, out, BT, DD, DD);
}

// Round 2
// 277.656 us; speedup vs baseline: 1.2800x; 1.2800x over previous
//
#include <hip/hip_runtime.h>
#include <hip/hip_bf16.h>
#include <stdint.h>

// ---------------- problem constants ----------------
#define BB 2
#define TT 2048
#define DD 2048
#define HH 16
#define KVH 8
#define HDIM 128
#define BT (BB*TT)            // 4096
#define NQKV (HH*HDIM + 2*KVH*HDIM) // 4096
#define TQ (TT/128)           // 16 q-blocks of 128 rows
#define ATT_SCALE 0.08838834764831845f
#define RMS_EPS 1e-6f

typedef __bf16 bf16;
typedef __bf16 bf16x8 __attribute__((ext_vector_type(8)));
typedef __bf16 bf16x4 __attribute__((ext_vector_type(4)));
typedef float  f32x4  __attribute__((ext_vector_type(4)));

// async global->LDS, 16B per lane. LDS dest = wave-uniform base + lane*16.
__device__ __forceinline__ void gl_lds16(const void* g, const void* l) {
  __builtin_amdgcn_global_load_lds(
      (const __attribute__((address_space(1))) void*)(uintptr_t)g,
      (__attribute__((address_space(3))) void*)(uint32_t)(uintptr_t)l,
      16, 0, 0);
}

// ---------------- elementwise f32 -> bf16 cast ----------------
__global__ __launch_bounds__(256) void cast_bf16_k(const float* __restrict__ in,
                                                   bf16* __restrict__ out, int n4) {
  int i = blockIdx.x * blockDim.x + threadIdx.x;
  int stride = gridDim.x * blockDim.x;
  for (; i < n4; i += stride) {
    float4 v = ((const float4*)in)[i];
    bf16x4 o = { (bf16)v.x, (bf16)v.y, (bf16)v.z, (bf16)v.w };
    *(bf16x4*)(out + (size_t)i * 4) = o;
  }
}

// ---------------- f32 (R x C) -> bf16 (C x R) transpose-cast ----------------
__global__ __launch_bounds__(256) void transpose_cast_k(const float* __restrict__ in,
                                                        bf16* __restrict__ out,
                                                        int R, int C) {
  __shared__ float tile[32][33];
  int tx = threadIdx.x & 31, ty = threadIdx.x >> 5;
  int c0 = blockIdx.x * 32, r0 = blockIdx.y * 32;
#pragma unroll
  for (int i = 0; i < 4; ++i)
    tile[ty + 8*i][tx] = in[(size_t)(r0 + ty + 8*i) * C + c0 + tx];
  __syncthreads();
#pragma unroll
  for (int i = 0; i < 4; ++i)
    out[(size_t)(c0 + ty + 8*i) * R + r0 + tx] = (bf16)tile[tx][ty + 8*i];
}

// ---------------- bf16 V transpose: (B,T,KV,HD) -> (B,KV,HD,T) ----------------
__global__ __launch_bounds__(256) void transpose_v_k(const bf16* __restrict__ vb,
                                                     bf16* __restrict__ vbt) {
  __shared__ bf16 tile[32][33];
  int tx = threadIdx.x & 31, ty = threadIdx.x >> 5;
  int t0 = blockIdx.x * 32;
  int d0 = blockIdx.y * 32;
  int bk = blockIdx.z;                 // b*KV + kv
  int b = bk >> 3, kv = bk & 7;
#pragma unroll
  for (int i = 0; i < 4; ++i)
    tile[ty + 8*i][tx] = vb[(((size_t)(b*TT + t0 + ty + 8*i)) * KVH + kv) * HDIM + d0 + tx];
  __syncthreads();
#pragma unroll
  for (int i = 0; i < 4; ++i)
    vbt[(((size_t)bk) * HDIM + d0 + ty + 8*i) * TT + t0 + tx] = tile[tx][ty + 8*i];
}

// ---------------- GEMM C = A(MxK) * Bt(NxK)^T, m97 structure ----------------
template <int OUT_F32>
__global__ __launch_bounds__(256, 2)
void gemm_bt_k(const bf16* __restrict__ A, const bf16* __restrict__ Bt,
               void* __restrict__ Cout, int M, int N, int K) {
  __shared__ bf16 As[128 * 32];
  __shared__ bf16 Bs[128 * 32];
  const int tid = threadIdx.x;
  const int lane = tid & 63, wid = tid >> 6;
  const int lr = lane & 15, lq = lane >> 4;
  const int bm = blockIdx.y * 128, bn = blockIdx.x * 128;
  const int wr = wid >> 1, wc = wid & 1;
  const bf16* Ab = A + (size_t)bm * K;
  const bf16* Bb = Bt + (size_t)bn * K;
  f32x4 acc[4][4] = {};
  for (int k0 = 0; k0 < K; k0 += 32) {
#pragma unroll
    for (int r = 0; r < 2; ++r) {
      int ch = r * 256 + tid;
      int row = ch >> 2, c8 = ch & 3;
      const bf16* lbase = As + (size_t)(r * 256 + wid * 64) * 8;
      gl_lds16(Ab + (size_t)row * K + k0 + c8 * 8, lbase);
      const bf16* lbase2 = Bs + (size_t)(r * 256 + wid * 64) * 8;
      gl_lds16(Bb + (size_t)row * K + k0 + c8 * 8, lbase2);
    }
    __syncthreads();
    bf16x8 af[4], bfv[4];
#pragma unroll
    for (int m = 0; m < 4; ++m)
      af[m] = *(const bf16x8*)&As[(wr * 64 + m * 16 + lr) * 32 + lq * 8];
#pragma unroll
    for (int n = 0; n < 4; ++n)
      bfv[n] = *(const bf16x8*)&Bs[(wc * 64 + n * 16 + lr) * 32 + lq * 8];
#pragma unroll
    for (int m = 0; m < 4; ++m)
#pragma unroll
      for (int n = 0; n < 4; ++n)
        acc[m][n] = __builtin_amdgcn_mfma_f32_16x16x32_bf16(af[m], bfv[n], acc[m][n], 0, 0, 0);
    __syncthreads();
  }
#pragma unroll
  for (int m = 0; m < 4; ++m)
#pragma unroll
    for (int n = 0; n < 4; ++n)
#pragma unroll
      for (int r = 0; r < 4; ++r) {
        int row = bm + wr * 64 + m * 16 + lq * 4 + r;
        int col = bn + wc * 64 + n * 16 + lr;
        if (OUT_F32) ((float*)Cout)[(size_t)row * N + col] = acc[m][n][r];
        else         ((bf16*)Cout)[(size_t)row * N + col] = (bf16)acc[m][n][r];
      }
}

// ---------------- fused RMSNorm + RoPE + split ----------------
__global__ __launch_bounds__(256) void norm_rope_k(const bf16* __restrict__ qkv,
                                                   const float* __restrict__ qn_w,
                                                   const float* __restrict__ kn_w,
                                                   const float* __restrict__ sinb,
                                                   const float* __restrict__ cosb,
                                                   bf16* __restrict__ qro,
                                                   bf16* __restrict__ kro,
                                                   bf16* __restrict__ vo) {
  const int bt = blockIdx.x;
  const int tid = threadIdx.x, lane = tid & 63, wid = tid >> 6;
  const bf16* row = qkv + (size_t)bt * NQKV;
  const float sv = sinb[bt * 64 + lane];
  const float cv = cosb[bt * 64 + lane];
  for (int it = 0; it < 8; ++it) {
    int hv = it * 4 + wid;   // 0..31 : 0-15 q, 16-23 k, 24-31 v
    int off = (hv < 16) ? hv * 128 : (hv < 24) ? 2048 + (hv - 16) * 128 : 3072 + (hv - 24) * 128;
    float e0 = (float)row[off + lane];
    float e1 = (float)row[off + 64 + lane];
    if (hv >= 24) {
      bf16* dst = vo + (size_t)bt * (KVH * HDIM) + (hv - 24) * 128;
      dst[lane] = (bf16)e0;
      dst[64 + lane] = (bf16)e1;
    } else {
      float ss = e0 * e0 + e1 * e1;
#pragma unroll
      for (int o = 32; o >= 1; o >>= 1) ss += __shfl_xor(ss, o, 64);
      float rms = rsqrtf(ss * (1.0f / 128.0f) + RMS_EPS);
      const float* wn = (hv < 16) ? qn_w : kn_w;
      float n0 = e0 * rms * wn[lane];
      float n1 = e1 * rms * wn[lane + 64];
      float o0 = n0 * cv - n1 * sv;
      float o1 = n1 * cv + n0 * sv;
      if (hv < 16) {
        bf16* dst = qro + (size_t)bt * (HH * HDIM) + hv * 128;
        dst[lane] = (bf16)o0; dst[64 + lane] = (bf16)o1;
      } else {
        bf16* dst = kro + (size_t)bt * (KVH * HDIM) + (hv - 16) * 128;
        dst[lane] = (bf16)o0; dst[64 + lane] = (bf16)o1;
      }
    }
  }
}

// ---------------- GQA causal flash attention, v2 ----------------
// grid (T/128, H, B); 8 waves (512 thr), each owns 16 q-rows (QBLK=128).
// KVBLK=64. K/V double-buffered in LDS, staged with pre-swizzled global src
// (chunk ^ (row&7)); 2-phase schedule: STAGE(next) -> compute(cur) -> barrier.
// For b=1, qt runs reversed so co-resident blocks have complementary work.
__global__ __launch_bounds__(512, 4)
void attn2_k(const bf16* __restrict__ qr, const bf16* __restrict__ kr,
             const bf16* __restrict__ vbt, bf16* __restrict__ ao) {
  __shared__ bf16 Ks[2][64 * 128];
  __shared__ bf16 Vs[2][128 * 64];
  __shared__ bf16 Ps[8 * 16 * 64];
  const int tid = threadIdx.x, lane = tid & 63, wid = tid >> 6;
  const int lr = lane & 15, lq = lane >> 4;
  const int h = blockIdx.y, b = blockIdx.z;
  const int qt = (b & 1) ? (TQ - 1 - blockIdx.x) : blockIdx.x;
  const int kvh = h >> 1;            // N_REP = 2
  const int qbase = qt * 128;
  const int q0 = qbase + wid * 16;
  const int nt = 2 * qt + 2;

  // staging geometry (16KB tile = 16 chunks of 1KB; each wave 2 chunks)
  const int krow0 = lane >> 4, kcc = lane & 15;   // K: row = chunk*4 + krow0
  const int vrow0 = lane >> 3, vcc = lane & 7;    // V: row = chunk*8 + vrow0

  auto STAGE = [&](int bufi, int kt) {
#pragma unroll
    for (int i = 0; i < 2; ++i) {
      int chunk = i * 8 + wid;
      int krow = chunk * 4 + krow0;
      gl_lds16(&kr[(((size_t)(b * TT + kt * 64 + krow)) * KVH + kvh) * HDIM + ((kcc ^ (krow & 7)) * 8)],
               &Ks[bufi][chunk * 512]);
      int drow = chunk * 8 + vrow0;
      gl_lds16(&vbt[(((size_t)(b * KVH + kvh)) * HDIM + drow) * TT + kt * 64 + ((vcc ^ (drow & 7)) * 8)],
               &Vs[bufi][chunk * 512]);
    }
  };

  bf16x8 aq[4];
#pragma unroll
  for (int kk = 0; kk < 4; ++kk)
    aq[kk] = *(const bf16x8*)&qr[(((size_t)(b * TT + q0 + lr)) * HH + h) * HDIM + kk * 32 + lq * 8];

  f32x4 accO[8] = {};
  float mrun[4], lrun[4];
#pragma unroll
  for (int r = 0; r < 4; ++r) { mrun[r] = -INFINITY; lrun[r] = 0.f; }

  int buf = 0;
  STAGE(0, 0);
  __syncthreads();

  for (int kt = 0; kt < nt; ++kt) {
    if (kt + 1 < nt) STAGE(buf ^ 1, kt + 1);

    if (kt * 64 <= q0 + 15) {   // wave-uniform: skip fully-masked tiles
      // ---- S = Q K^T ----
      f32x4 sacc[4];
#pragma unroll
      for (int ct = 0; ct < 4; ++ct) {
        sacc[ct] = (f32x4){0.f, 0.f, 0.f, 0.f};
        int krow = ct * 16 + lr;
#pragma unroll
        for (int kk = 0; kk < 4; ++kk) {
          bf16x8 bk = *(const bf16x8*)((const char*)&Ks[buf][0] + krow * 256 + (((kk * 4 + lq) ^ (krow & 7)) * 16));
          sacc[ct] = __builtin_amdgcn_mfma_f32_16x16x32_bf16(aq[kk], bk, sacc[ct], 0, 0, 0);
        }
      }

      // ---- mask, scale, online softmax ----
      const bool domask = (kt * 64 + 63 > q0);
      float p[4][4];
      float pm[4] = {-INFINITY, -INFINITY, -INFINITY, -INFINITY};
#pragma unroll
      for (int ct = 0; ct < 4; ++ct) {
        int col = kt * 64 + ct * 16 + lr;
#pragma unroll
        for (int r = 0; r < 4; ++r) {
          int rowg = q0 + lq * 4 + r;
          float s = (!domask || col <= rowg) ? sacc[ct][r] * ATT_SCALE : -INFINITY;
          p[ct][r] = s;
          pm[r] = fmaxf(pm[r], s);
        }
      }
#pragma unroll
      for (int r = 0; r < 4; ++r) {
#pragma unroll
        for (int o = 1; o < 16; o <<= 1) pm[r] = fmaxf(pm[r], __shfl_xor(pm[r], o, 64));
      }
      float alpha[4], mnew[4];
#pragma unroll
      for (int r = 0; r < 4; ++r) {
        mnew[r] = fmaxf(mrun[r], pm[r]);
        alpha[r] = __expf(mrun[r] - mnew[r]);
        mrun[r] = mnew[r];
      }
      float rs[4] = {0.f, 0.f, 0.f, 0.f};
#pragma unroll
      for (int ct = 0; ct < 4; ++ct)
#pragma unroll
        for (int r = 0; r < 4; ++r) {
          float e = __expf(p[ct][r] - mnew[r]);
          p[ct][r] = e;
          rs[r] += e;
        }
#pragma unroll
      for (int r = 0; r < 4; ++r) {
#pragma unroll
        for (int o = 1; o < 16; o <<= 1) rs[r] += __shfl_xor(rs[r], o, 64);
        lrun[r] = lrun[r] * alpha[r] + rs[r];
      }

      // ---- write P to per-wave swizzled LDS ----
#pragma unroll
      for (int ct = 0; ct < 4; ++ct)
#pragma unroll
        for (int r = 0; r < 4; ++r) {
          int prow = lq * 4 + r;
          int col = ct * 16 + lr;
          int cc = col >> 3;
          char* pb = (char*)Ps + (wid * 16 + prow) * 128 + ((cc ^ (prow & 7)) * 16) + (col & 7) * 2;
          *(bf16*)pb = (bf16)p[ct][r];
        }

      // ---- rescale O ----
#pragma unroll
      for (int n = 0; n < 8; ++n)
#pragma unroll
        for (int r = 0; r < 4; ++r) accO[n][r] *= alpha[r];

      // ---- O += P V ----
#pragma unroll
      for (int c = 0; c < 2; ++c) {
        bf16x8 ap = *(const bf16x8*)((const char*)Ps + (wid * 16 + lr) * 128 + (((c * 4 + lq) ^ (lr & 7)) * 16));
#pragma unroll
        for (int n = 0; n < 8; ++n) {
          int drow = n * 16 + lr;
          bf16x8 bv = *(const bf16x8*)((const char*)&Vs[buf][0] + drow * 128 + (((c * 4 + lq) ^ (drow & 7)) * 16));
          accO[n] = __builtin_amdgcn_mfma_f32_16x16x32_bf16(ap, bv, accO[n], 0, 0, 0);
        }
      }
    }

    __syncthreads();   // drains vmcnt: next tile staged & this tile's reads done
    buf ^= 1;
  }

  float inv[4];
#pragma unroll
  for (int r = 0; r < 4; ++r) inv[r] = 1.0f / lrun[r];
#pragma unroll
  for (int n = 0; n < 8; ++n)
#pragma unroll
    for (int r = 0; r < 4; ++r) {
      size_t idx = (((size_t)(b * TT + q0 + lq * 4 + r)) * HH + h) * HDIM + n * 16 + lr;
      ao[idx] = (bf16)(accO[n][r] * inv[r]);
    }
}

// ---------------- launcher ----------------
extern "C" void kernel_launch(void* const* d_in, const int* in_sizes, int n_in,
                              void* d_out, int out_size, void* d_ws, size_t ws_size,
                              hipStream_t stream) {
  const float* x    = (const float*)d_in[0];
  const float* wq   = (const float*)d_in[1];
  const float* wk   = (const float*)d_in[2];
  const float* wv   = (const float*)d_in[3];
  const float* wo   = (const float*)d_in[4];
  const float* qn_w = (const float*)d_in[5];
  const float* kn_w = (const float*)d_in[6];
  const float* sinb = (const float*)d_in[7];
  const float* cosb = (const float*)d_in[8];
  float* out = (float*)d_out;

  char* ws = (char*)d_ws;
  size_t off = 0;
  auto alloc = [&](size_t bytes) {
    char* p = ws + off;
    off += (bytes + 255) & ~(size_t)255;
    return p;
  };
  bf16* xb  = (bf16*)alloc((size_t)BT * DD * 2);       // x bf16 (reused as attn out)
  bf16* Wt  = (bf16*)alloc((size_t)NQKV * DD * 2);     // [wq|wk|wv]^T (reused as q_rope)
  bf16* Wot = (bf16*)alloc((size_t)DD * DD * 2);       // wo^T
  bf16* qkv = (bf16*)alloc((size_t)BT * NQKV * 2);     // fused qkv
  bf16* kro = (bf16*)alloc((size_t)BT * KVH * HDIM * 2);
  bf16* vb  = (bf16*)alloc((size_t)BT * KVH * HDIM * 2);
  bf16* vbt = (bf16*)alloc((size_t)BT * KVH * HDIM * 2);
  bf16* qro = Wt;   // alias: Wt dead after QKV GEMM
  bf16* aob = xb;   // alias: xb dead after QKV GEMM
  (void)ws_size; (void)in_sizes; (void)n_in; (void)out_size;

  cast_bf16_k<<<2048, 256, 0, stream>>>(x, xb, BT * DD / 4);
  transpose_cast_k<<<dim3(2048 / 32, 2048 / 32), 256, 0, stream>>>(wq, Wt, 2048, 2048);
  transpose_cast_k<<<dim3(1024 / 32, 2048 / 32), 256, 0, stream>>>(wk, Wt + (size_t)2048 * 2048, 2048, 1024);
  transpose_cast_k<<<dim3(1024 / 32, 2048 / 32), 256, 0, stream>>>(wv, Wt + (size_t)3072 * 2048, 2048, 1024);
  transpose_cast_k<<<dim3(2048 / 32, 2048 / 32), 256, 0, stream>>>(wo, Wot, 2048, 2048);

  gemm_bt_k<0><<<dim3(NQKV / 128, BT / 128), 256, 0, stream>>>(xb, Wt, qkv, BT, NQKV, DD);

  norm_rope_k<<<BT, 256, 0, stream>>>(qkv, qn_w, kn_w, sinb, cosb, qro, kro, vb);
  transpose_v_k<<<dim3(TT / 32, HDIM / 32, BB * KVH), 256, 0, stream>>>(vb, vbt);

  attn2_k<<<dim3(TQ, HH, BB), 512, 0, stream>>>(qro, kro, vbt, aob);

  gemm_bt_k<1><<<dim3(DD / 128, BT / 128), 256, 0, stream>>>(aob, Wot, out, BT, DD, DD);
}

// Round 3
// 270.355 us; speedup vs baseline: 1.3146x; 1.0270x over previous
//
#include <hip/hip_runtime.h>
#include <hip/hip_bf16.h>
#include <stdint.h>

// ---------------- problem constants ----------------
#define BB 2
#define TT 2048
#define DD 2048
#define HH 16
#define KVH 8
#define HDIM 128
#define BT (BB*TT)            // 4096
#define NQKV (HH*HDIM + 2*KVH*HDIM) // 4096
#define TQ (TT/128)           // 16 q-blocks of 128 rows
#define ATT_SCALE 0.08838834764831845f
#define RMS_EPS 1e-6f

typedef __bf16 bf16;
typedef __bf16 bf16x8 __attribute__((ext_vector_type(8)));
typedef __bf16 bf16x4 __attribute__((ext_vector_type(4)));
typedef float  f32x4  __attribute__((ext_vector_type(4)));

// async global->LDS, 16B per lane. LDS dest = wave-uniform base + lane*16.
__device__ __forceinline__ void gl_lds16(const void* g, const void* l) {
  __builtin_amdgcn_global_load_lds(
      (const __attribute__((address_space(1))) void*)(uintptr_t)g,
      (__attribute__((address_space(3))) void*)(uint32_t)(uintptr_t)l,
      16, 0, 0);
}

// ---------------- elementwise f32 -> bf16 cast ----------------
__global__ __launch_bounds__(256) void cast_bf16_k(const float* __restrict__ in,
                                                   bf16* __restrict__ out, int n4) {
  int i = blockIdx.x * blockDim.x + threadIdx.x;
  int stride = gridDim.x * blockDim.x;
  for (; i < n4; i += stride) {
    float4 v = ((const float4*)in)[i];
    bf16x4 o = { (bf16)v.x, (bf16)v.y, (bf16)v.z, (bf16)v.w };
    *(bf16x4*)(out + (size_t)i * 4) = o;
  }
}

// ---------------- f32 (R x C) -> bf16 (C x R) transpose-cast ----------------
__global__ __launch_bounds__(256) void transpose_cast_k(const float* __restrict__ in,
                                                        bf16* __restrict__ out,
                                                        int R, int C) {
  __shared__ float tile[32][33];
  int tx = threadIdx.x & 31, ty = threadIdx.x >> 5;
  int c0 = blockIdx.x * 32, r0 = blockIdx.y * 32;
#pragma unroll
  for (int i = 0; i < 4; ++i)
    tile[ty + 8*i][tx] = in[(size_t)(r0 + ty + 8*i) * C + c0 + tx];
  __syncthreads();
#pragma unroll
  for (int i = 0; i < 4; ++i)
    out[(size_t)(c0 + ty + 8*i) * R + r0 + tx] = (bf16)tile[tx][ty + 8*i];
}

// ---------------- bf16 V transpose: (B,T,KV,HD) -> (B,KV,HD,T) ----------------
__global__ __launch_bounds__(256) void transpose_v_k(const bf16* __restrict__ vb,
                                                     bf16* __restrict__ vbt) {
  __shared__ bf16 tile[32][33];
  int tx = threadIdx.x & 31, ty = threadIdx.x >> 5;
  int t0 = blockIdx.x * 32;
  int d0 = blockIdx.y * 32;
  int bk = blockIdx.z;                 // b*KV + kv
  int b = bk >> 3, kv = bk & 7;
#pragma unroll
  for (int i = 0; i < 4; ++i)
    tile[ty + 8*i][tx] = vb[(((size_t)(b*TT + t0 + ty + 8*i)) * KVH + kv) * HDIM + d0 + tx];
  __syncthreads();
#pragma unroll
  for (int i = 0; i < 4; ++i)
    vbt[(((size_t)bk) * HDIM + d0 + ty + 8*i) * TT + t0 + tx] = tile[tx][ty + 8*i];
}

// ---------------- GEMM C = A(MxK) * Bt(NxK)^T, m97 structure (128x128) ----------------
template <int OUT_F32>
__global__ __launch_bounds__(256, 2)
void gemm_bt_k(const bf16* __restrict__ A, const bf16* __restrict__ Bt,
               void* __restrict__ Cout, int M, int N, int K) {
  __shared__ bf16 As[128 * 32];
  __shared__ bf16 Bs[128 * 32];
  const int tid = threadIdx.x;
  const int lane = tid & 63, wid = tid >> 6;
  const int lr = lane & 15, lq = lane >> 4;
  const int bm = blockIdx.y * 128, bn = blockIdx.x * 128;
  const int wr = wid >> 1, wc = wid & 1;
  const bf16* Ab = A + (size_t)bm * K;
  const bf16* Bb = Bt + (size_t)bn * K;
  f32x4 acc[4][4] = {};
  for (int k0 = 0; k0 < K; k0 += 32) {
#pragma unroll
    for (int r = 0; r < 2; ++r) {
      int ch = r * 256 + tid;
      int row = ch >> 2, c8 = ch & 3;
      const bf16* lbase = As + (size_t)(r * 256 + wid * 64) * 8;
      gl_lds16(Ab + (size_t)row * K + k0 + c8 * 8, lbase);
      const bf16* lbase2 = Bs + (size_t)(r * 256 + wid * 64) * 8;
      gl_lds16(Bb + (size_t)row * K + k0 + c8 * 8, lbase2);
    }
    __syncthreads();
    bf16x8 af[4], bfv[4];
#pragma unroll
    for (int m = 0; m < 4; ++m)
      af[m] = *(const bf16x8*)&As[(wr * 64 + m * 16 + lr) * 32 + lq * 8];
#pragma unroll
    for (int n = 0; n < 4; ++n)
      bfv[n] = *(const bf16x8*)&Bs[(wc * 64 + n * 16 + lr) * 32 + lq * 8];
#pragma unroll
    for (int m = 0; m < 4; ++m)
#pragma unroll
      for (int n = 0; n < 4; ++n)
        acc[m][n] = __builtin_amdgcn_mfma_f32_16x16x32_bf16(af[m], bfv[n], acc[m][n], 0, 0, 0);
    __syncthreads();
  }
#pragma unroll
  for (int m = 0; m < 4; ++m)
#pragma unroll
    for (int n = 0; n < 4; ++n)
#pragma unroll
      for (int r = 0; r < 4; ++r) {
        int row = bm + wr * 64 + m * 16 + lq * 4 + r;
        int col = bn + wc * 64 + n * 16 + lr;
        if (OUT_F32) ((float*)Cout)[(size_t)row * N + col] = acc[m][n][r];
        else         ((bf16*)Cout)[(size_t)row * N + col] = (bf16)acc[m][n][r];
      }
}

// ---------------- GEMM 256x256, BK=64, 8-phase counted-vmcnt schedule ----------------
// 8 waves (2 Mrows x 4... actually 4x2: wrow=wid>>1 (0..3) x wcol=wid&1 (0..1)).
// Quadrants of block C (128x128 each), per quadrant each wave computes 32x64.
// Quadrant order (0,0),(1,0),(1,1),(0,1) so A halves (both cached) and B halves
// (cached per 2 phases) give 24 ds_read_b128 per K-tile.
// Staging: 1 half-operand per phase: ph1 B1(t+1), ph2 A0(t+2), ph3 A1(t+2),
// ph4 B0(t+2); vmcnt(6) once per tile at ph4. Raw s_barrier (no vmcnt drain).
// LDS: [buf 2][op 2][half 2][128 rows][64 k] bf16, row-XOR chunk swizzle.
template <int OUT_F32>
__global__ __launch_bounds__(512, 2)
void gemm256_k(const bf16* __restrict__ A, const bf16* __restrict__ Bt,
               void* __restrict__ Cout, int M, int N, int K) {
  __shared__ bf16 S[2 * 2 * 2 * 128 * 64];   // 128 KiB
  const int tid = threadIdx.x, lane = tid & 63, wid = tid >> 6;
  const int lr = lane & 15, lq = lane >> 4;
  const int wrow = wid >> 1, wcol = wid & 1;

  // XCD-aware bijective swizzle of the flat block id (nwg % 8 == 0 here)
  const int nwg = gridDim.x;
  const int o = blockIdx.x;
  const int ns = (o & 7) * (nwg >> 3) + (o >> 3);
  const int GX = N >> 8;
  const int by = ns / GX, bx = ns % GX;

  const int NT = K >> 6;
  const bf16* Ab = A + (size_t)(by * 256) * K;
  const bf16* Bb = Bt + (size_t)(bx * 256) * K;

  // staging per-thread geometry: row = i*64 + (tid>>3), chunk = tid&7 (16B)
  const int srow = tid >> 3;
  const size_t soff = (size_t)srow * K + (((tid & 7) ^ (srow & 7)) * 8);
  const int ldst0 = wid * 512;               // elements; +i*4096

  auto STAGE = [&](int op, int h, int t_) {
    int tc = t_ < NT ? t_ : NT - 1;
    const bf16* src = (op ? Bb : Ab) + soff + (size_t)(h * 128) * K + tc * 64;
    bf16* dst = S + ((((((t_ & 1) << 1) | op) << 1) | h) << 13) + ldst0;
#pragma unroll
    for (int i = 0; i < 2; ++i)
      gl_lds16(src + (size_t)(i * 64) * K, dst + i * 4096);
  };

  bf16x8 af[2][2][2];   // [mh][m][ks]
  bf16x8 bfr[4][2];     // [n][ks]
  f32x4 acc[4][2][4] = {};  // [quad][m][n]

  auto LOAD_A = [&](int buf) {
#pragma unroll
    for (int mh = 0; mh < 2; ++mh) {
      const bf16* base = S + (((buf << 2) | mh) << 13);     // op=0
#pragma unroll
      for (int m = 0; m < 2; ++m) {
        int ra = wrow * 32 + m * 16 + lr;
#pragma unroll
        for (int ks = 0; ks < 2; ++ks)
          af[mh][m][ks] = *(const bf16x8*)(base + ra * 64 + (((ks * 4 + lq) ^ (ra & 7)) * 8));
      }
    }
  };
  auto LOAD_B = [&](int buf, int nh) {
    const bf16* base = S + (((buf << 2) | 2 | nh) << 13);   // op=1
#pragma unroll
    for (int n = 0; n < 4; ++n) {
      int rb = wcol * 64 + n * 16 + lr;
#pragma unroll
      for (int ks = 0; ks < 2; ++ks)
        bfr[n][ks] = *(const bf16x8*)(base + rb * 64 + (((ks * 4 + lq) ^ (rb & 7)) * 8));
    }
  };
  auto MFMA_Q = [&](int qd, int mh) {
#pragma unroll
    for (int m = 0; m < 2; ++m)
#pragma unroll
      for (int n = 0; n < 4; ++n)
#pragma unroll
        for (int ks = 0; ks < 2; ++ks)
          acc[qd][m][n] = __builtin_amdgcn_mfma_f32_16x16x32_bf16(
              af[mh][m][ks], bfr[n][ks], acc[qd][m][n], 0, 0, 0);
  };

  // prologue: A0(0) A1(0) B0(0) B1(0) A0(1) A1(1) B0(1), then wait 4 halves
  STAGE(0, 0, 0); STAGE(0, 1, 0); STAGE(1, 0, 0); STAGE(1, 1, 0);
  STAGE(0, 0, 1); STAGE(0, 1, 1); STAGE(1, 0, 1);
  asm volatile("s_waitcnt vmcnt(6)" ::: "memory");
  __builtin_amdgcn_sched_barrier(0);
  __builtin_amdgcn_s_barrier();

  for (int t = 0; t < NT; ++t) {
    const int buf = t & 1;
    // ---- phase 1: Q(0,0); reads A0,A1,B0; stage B1(t+1) ----
    LOAD_A(buf);
    LOAD_B(buf, 0);
    STAGE(1, 1, t + 1);
    __builtin_amdgcn_s_barrier();
    asm volatile("s_waitcnt lgkmcnt(0)" ::: "memory");
    __builtin_amdgcn_sched_barrier(0);
    __builtin_amdgcn_s_setprio(1);
    MFMA_Q(0, 0);
    __builtin_amdgcn_s_setprio(0);
    __builtin_amdgcn_sched_barrier(0);
    __builtin_amdgcn_s_barrier();
    // ---- phase 2: Q(1,0); cached A1,B0; stage A0(t+2) ----
    STAGE(0, 0, t + 2);
    __builtin_amdgcn_s_barrier();
    __builtin_amdgcn_s_setprio(1);
    MFMA_Q(1, 1);
    __builtin_amdgcn_s_setprio(0);
    __builtin_amdgcn_sched_barrier(0);
    __builtin_amdgcn_s_barrier();
    // ---- phase 3: Q(1,1); reads B1; stage A1(t+2) ----
    LOAD_B(buf, 1);
    STAGE(0, 1, t + 2);
    __builtin_amdgcn_s_barrier();
    asm volatile("s_waitcnt lgkmcnt(0)" ::: "memory");
    __builtin_amdgcn_sched_barrier(0);
    __builtin_amdgcn_s_setprio(1);
    MFMA_Q(2, 1);
    __builtin_amdgcn_s_setprio(0);
    __builtin_amdgcn_sched_barrier(0);
    __builtin_amdgcn_s_barrier();
    // ---- phase 4: Q(0,1); cached A0,B1; stage B0(t+2); vmcnt(6) ----
    STAGE(1, 0, t + 2);
    asm volatile("s_waitcnt vmcnt(6)" ::: "memory");
    __builtin_amdgcn_sched_barrier(0);
    __builtin_amdgcn_s_barrier();
    __builtin_amdgcn_s_setprio(1);
    MFMA_Q(3, 0);
    __builtin_amdgcn_s_setprio(0);
    __builtin_amdgcn_sched_barrier(0);
    __builtin_amdgcn_s_barrier();
  }

  // epilogue: quad qd -> (mh,nh): 0:(0,0) 1:(1,0) 2:(1,1) 3:(0,1)
#pragma unroll
  for (int qd = 0; qd < 4; ++qd) {
    const int mh = (qd == 1 || qd == 2) ? 1 : 0;
    const int nh = (qd >= 2) ? 1 : 0;
#pragma unroll
    for (int m = 0; m < 2; ++m)
#pragma unroll
      for (int n = 0; n < 4; ++n)
#pragma unroll
        for (int j = 0; j < 4; ++j) {
          int row = by * 256 + mh * 128 + wrow * 32 + m * 16 + lq * 4 + j;
          int col = bx * 256 + nh * 128 + wcol * 64 + n * 16 + lr;
          if (OUT_F32) ((float*)Cout)[(size_t)row * N + col] = acc[qd][m][n][j];
          else         ((bf16*)Cout)[(size_t)row * N + col] = (bf16)acc[qd][m][n][j];
        }
  }
}

// ---------------- fused RMSNorm + RoPE + split ----------------
__global__ __launch_bounds__(256) void norm_rope_k(const bf16* __restrict__ qkv,
                                                   const float* __restrict__ qn_w,
                                                   const float* __restrict__ kn_w,
                                                   const float* __restrict__ sinb,
                                                   const float* __restrict__ cosb,
                                                   bf16* __restrict__ qro,
                                                   bf16* __restrict__ kro,
                                                   bf16* __restrict__ vo) {
  const int bt = blockIdx.x;
  const int tid = threadIdx.x, lane = tid & 63, wid = tid >> 6;
  const bf16* row = qkv + (size_t)bt * NQKV;
  const float sv = sinb[bt * 64 + lane];
  const float cv = cosb[bt * 64 + lane];
  for (int it = 0; it < 8; ++it) {
    int hv = it * 4 + wid;   // 0..31 : 0-15 q, 16-23 k, 24-31 v
    int off = (hv < 16) ? hv * 128 : (hv < 24) ? 2048 + (hv - 16) * 128 : 3072 + (hv - 24) * 128;
    float e0 = (float)row[off + lane];
    float e1 = (float)row[off + 64 + lane];
    if (hv >= 24) {
      bf16* dst = vo + (size_t)bt * (KVH * HDIM) + (hv - 24) * 128;
      dst[lane] = (bf16)e0;
      dst[64 + lane] = (bf16)e1;
    } else {
      float ss = e0 * e0 + e1 * e1;
#pragma unroll
      for (int o = 32; o >= 1; o >>= 1) ss += __shfl_xor(ss, o, 64);
      float rms = rsqrtf(ss * (1.0f / 128.0f) + RMS_EPS);
      const float* wn = (hv < 16) ? qn_w : kn_w;
      float n0 = e0 * rms * wn[lane];
      float n1 = e1 * rms * wn[lane + 64];
      float o0 = n0 * cv - n1 * sv;
      float o1 = n1 * cv + n0 * sv;
      if (hv < 16) {
        bf16* dst = qro + (size_t)bt * (HH * HDIM) + hv * 128;
        dst[lane] = (bf16)o0; dst[64 + lane] = (bf16)o1;
      } else {
        bf16* dst = kro + (size_t)bt * (KVH * HDIM) + (hv - 16) * 128;
        dst[lane] = (bf16)o0; dst[64 + lane] = (bf16)o1;
      }
    }
  }
}

// ---------------- GQA causal flash attention, v2 + setprio ----------------
__global__ __launch_bounds__(512, 4)
void attn2_k(const bf16* __restrict__ qr, const bf16* __restrict__ kr,
             const bf16* __restrict__ vbt, bf16* __restrict__ ao) {
  __shared__ bf16 Ks[2][64 * 128];
  __shared__ bf16 Vs[2][128 * 64];
  __shared__ bf16 Ps[8 * 16 * 64];
  const int tid = threadIdx.x, lane = tid & 63, wid = tid >> 6;
  const int lr = lane & 15, lq = lane >> 4;
  const int h = blockIdx.y, b = blockIdx.z;
  const int qt = (b & 1) ? (TQ - 1 - blockIdx.x) : blockIdx.x;
  const int kvh = h >> 1;            // N_REP = 2
  const int q0 = qt * 128 + wid * 16;
  const int nt = 2 * qt + 2;

  const int krow0 = lane >> 4, kcc = lane & 15;   // K: row = chunk*4 + krow0
  const int vrow0 = lane >> 3, vcc = lane & 7;    // V: row = chunk*8 + vrow0

  auto STAGE = [&](int bufi, int kt) {
#pragma unroll
    for (int i = 0; i < 2; ++i) {
      int chunk = i * 8 + wid;
      int krow = chunk * 4 + krow0;
      gl_lds16(&kr[(((size_t)(b * TT + kt * 64 + krow)) * KVH + kvh) * HDIM + ((kcc ^ (krow & 7)) * 8)],
               &Ks[bufi][chunk * 512]);
      int drow = chunk * 8 + vrow0;
      gl_lds16(&vbt[(((size_t)(b * KVH + kvh)) * HDIM + drow) * TT + kt * 64 + ((vcc ^ (drow & 7)) * 8)],
               &Vs[bufi][chunk * 512]);
    }
  };

  bf16x8 aq[4];
#pragma unroll
  for (int kk = 0; kk < 4; ++kk)
    aq[kk] = *(const bf16x8*)&qr[(((size_t)(b * TT + q0 + lr)) * HH + h) * HDIM + kk * 32 + lq * 8];

  f32x4 accO[8] = {};
  float mrun[4], lrun[4];
#pragma unroll
  for (int r = 0; r < 4; ++r) { mrun[r] = -INFINITY; lrun[r] = 0.f; }

  int buf = 0;
  STAGE(0, 0);
  __syncthreads();

  for (int kt = 0; kt < nt; ++kt) {
    if (kt + 1 < nt) STAGE(buf ^ 1, kt + 1);

    if (kt * 64 <= q0 + 15) {   // wave-uniform: skip fully-masked tiles
      // ---- S = Q K^T ----
      f32x4 sacc[4];
      __builtin_amdgcn_s_setprio(1);
#pragma unroll
      for (int ct = 0; ct < 4; ++ct) {
        sacc[ct] = (f32x4){0.f, 0.f, 0.f, 0.f};
        int krow = ct * 16 + lr;
#pragma unroll
        for (int kk = 0; kk < 4; ++kk) {
          bf16x8 bk = *(const bf16x8*)((const char*)&Ks[buf][0] + krow * 256 + (((kk * 4 + lq) ^ (krow & 7)) * 16));
          sacc[ct] = __builtin_amdgcn_mfma_f32_16x16x32_bf16(aq[kk], bk, sacc[ct], 0, 0, 0);
        }
      }
      __builtin_amdgcn_s_setprio(0);

      // ---- mask, scale, online softmax ----
      const bool domask = (kt * 64 + 63 > q0);
      float p[4][4];
      float pm[4] = {-INFINITY, -INFINITY, -INFINITY, -INFINITY};
#pragma unroll
      for (int ct = 0; ct < 4; ++ct) {
        int col = kt * 64 + ct * 16 + lr;
#pragma unroll
        for (int r = 0; r < 4; ++r) {
          int rowg = q0 + lq * 4 + r;
          float s = (!domask || col <= rowg) ? sacc[ct][r] * ATT_SCALE : -INFINITY;
          p[ct][r] = s;
          pm[r] = fmaxf(pm[r], s);
        }
      }
#pragma unroll
      for (int r = 0; r < 4; ++r) {
#pragma unroll
        for (int o = 1; o < 16; o <<= 1) pm[r] = fmaxf(pm[r], __shfl_xor(pm[r], o, 64));
      }
      float alpha[4], mnew[4];
#pragma unroll
      for (int r = 0; r < 4; ++r) {
        mnew[r] = fmaxf(mrun[r], pm[r]);
        alpha[r] = __expf(mrun[r] - mnew[r]);
        mrun[r] = mnew[r];
      }
      float rs[4] = {0.f, 0.f, 0.f, 0.f};
#pragma unroll
      for (int ct = 0; ct < 4; ++ct)
#pragma unroll
        for (int r = 0; r < 4; ++r) {
          float e = __expf(p[ct][r] - mnew[r]);
          p[ct][r] = e;
          rs[r] += e;
        }
#pragma unroll
      for (int r = 0; r < 4; ++r) {
#pragma unroll
        for (int o = 1; o < 16; o <<= 1) rs[r] += __shfl_xor(rs[r], o, 64);
        lrun[r] = lrun[r] * alpha[r] + rs[r];
      }

      // ---- write P to per-wave swizzled LDS ----
#pragma unroll
      for (int ct = 0; ct < 4; ++ct)
#pragma unroll
        for (int r = 0; r < 4; ++r) {
          int prow = lq * 4 + r;
          int col = ct * 16 + lr;
          int cc = col >> 3;
          char* pb = (char*)Ps + (wid * 16 + prow) * 128 + ((cc ^ (prow & 7)) * 16) + (col & 7) * 2;
          *(bf16*)pb = (bf16)p[ct][r];
        }

      // ---- rescale O ----
#pragma unroll
      for (int n = 0; n < 8; ++n)
#pragma unroll
        for (int r = 0; r < 4; ++r) accO[n][r] *= alpha[r];

      // ---- O += P V ----
      __builtin_amdgcn_s_setprio(1);
#pragma unroll
      for (int c = 0; c < 2; ++c) {
        bf16x8 ap = *(const bf16x8*)((const char*)Ps + (wid * 16 + lr) * 128 + (((c * 4 + lq) ^ (lr & 7)) * 16));
#pragma unroll
        for (int n = 0; n < 8; ++n) {
          int drow = n * 16 + lr;
          bf16x8 bv = *(const bf16x8*)((const char*)&Vs[buf][0] + drow * 128 + (((c * 4 + lq) ^ (drow & 7)) * 16));
          accO[n] = __builtin_amdgcn_mfma_f32_16x16x32_bf16(ap, bv, accO[n], 0, 0, 0);
        }
      }
      __builtin_amdgcn_s_setprio(0);
    }

    __syncthreads();   // drains vmcnt: next tile staged & this tile's reads done
    buf ^= 1;
  }

  float inv[4];
#pragma unroll
  for (int r = 0; r < 4; ++r) inv[r] = 1.0f / lrun[r];
#pragma unroll
  for (int n = 0; n < 8; ++n)
#pragma unroll
    for (int r = 0; r < 4; ++r) {
      size_t idx = (((size_t)(b * TT + q0 + lq * 4 + r)) * HH + h) * HDIM + n * 16 + lr;
      ao[idx] = (bf16)(accO[n][r] * inv[r]);
    }
}

// ---------------- launcher ----------------
extern "C" void kernel_launch(void* const* d_in, const int* in_sizes, int n_in,
                              void* d_out, int out_size, void* d_ws, size_t ws_size,
                              hipStream_t stream) {
  const float* x    = (const float*)d_in[0];
  const float* wq   = (const float*)d_in[1];
  const float* wk   = (const float*)d_in[2];
  const float* wv   = (const float*)d_in[3];
  const float* wo   = (const float*)d_in[4];
  const float* qn_w = (const float*)d_in[5];
  const float* kn_w = (const float*)d_in[6];
  const float* sinb = (const float*)d_in[7];
  const float* cosb = (const float*)d_in[8];
  float* out = (float*)d_out;

  char* ws = (char*)d_ws;
  size_t off = 0;
  auto alloc = [&](size_t bytes) {
    char* p = ws + off;
    off += (bytes + 255) & ~(size_t)255;
    return p;
  };
  bf16* xb  = (bf16*)alloc((size_t)BT * DD * 2);       // x bf16 (reused as attn out)
  bf16* Wt  = (bf16*)alloc((size_t)NQKV * DD * 2);     // [wq|wk|wv]^T (reused as q_rope)
  bf16* Wot = (bf16*)alloc((size_t)DD * DD * 2);       // wo^T
  bf16* qkv = (bf16*)alloc((size_t)BT * NQKV * 2);     // fused qkv
  bf16* kro = (bf16*)alloc((size_t)BT * KVH * HDIM * 2);
  bf16* vb  = (bf16*)alloc((size_t)BT * KVH * HDIM * 2);
  bf16* vbt = (bf16*)alloc((size_t)BT * KVH * HDIM * 2);
  bf16* qro = Wt;   // alias: Wt dead after QKV GEMM
  bf16* aob = xb;   // alias: xb dead after QKV GEMM
  (void)ws_size; (void)in_sizes; (void)n_in; (void)out_size;

  cast_bf16_k<<<2048, 256, 0, stream>>>(x, xb, BT * DD / 4);
  transpose_cast_k<<<dim3(2048 / 32, 2048 / 32), 256, 0, stream>>>(wq, Wt, 2048, 2048);
  transpose_cast_k<<<dim3(1024 / 32, 2048 / 32), 256, 0, stream>>>(wk, Wt + (size_t)2048 * 2048, 2048, 1024);
  transpose_cast_k<<<dim3(1024 / 32, 2048 / 32), 256, 0, stream>>>(wv, Wt + (size_t)3072 * 2048, 2048, 1024);
  transpose_cast_k<<<dim3(2048 / 32, 2048 / 32), 256, 0, stream>>>(wo, Wot, 2048, 2048);

  // QKV GEMM: 256^2 8-phase (M=4096, N=4096 -> 256 blocks, 1/CU)
  gemm256_k<0><<<dim3((BT / 256) * (NQKV / 256)), 512, 0, stream>>>(xb, Wt, qkv, BT, NQKV, DD);

  norm_rope_k<<<BT, 256, 0, stream>>>(qkv, qn_w, kn_w, sinb, cosb, qro, kro, vb);
  transpose_v_k<<<dim3(TT / 32, HDIM / 32, BB * KVH), 256, 0, stream>>>(vb, vbt);

  attn2_k<<<dim3(TQ, HH, BB), 512, 0, stream>>>(qro, kro, vbt, aob);

  gemm_bt_k<1><<<dim3(DD / 128, BT / 128), 256, 0, stream>>>(aob, Wot, out, BT, DD, DD);
}